// Round 20
// baseline (51.777 us; speedup 1.0000x reference)
//
#include <hip/hip_runtime.h>
#include <math.h>

#define N_IN  96
#define N_OUT 192
#define BW    24    // truncated band window width (pass_x only)
#define TSP   104   // TzT tile row stride in halfs (208B: 16B-aligned, 2-way max)

typedef _Float16 h2    __attribute__((ext_vector_type(2)));
typedef _Float16 v8h   __attribute__((ext_vector_type(8)));
typedef float    f32x4 __attribute__((ext_vector_type(4)));

__device__ __forceinline__ unsigned int packh2(float a, float b) {
    h2 h; h.x = (_Float16)a; h.y = (_Float16)b;
    return __builtin_bit_cast(unsigned int, h);
}

__device__ __forceinline__ void fma4(float4& a, float w, const float4& v) {
    a.x += w * v.x; a.y += w * v.y; a.z += w * v.z; a.w += w * v.w;
}

__device__ __forceinline__ v8h as8h(const uint4& u) {
    return __builtin_bit_cast(v8h, u);
}

// ---------------- compile-time weight tables ----------------
// M = B_resize(192x96) * A^-1 (A tridiag: diag 2/3, 5/6 at ends, off 1/6),
// constexpr Thomas solve.
//  WB8T/S8 : banded f32 weights for pass_x (window BW=24).
//  BF      : dense fp16 M in mfma_f32_16x16x32_f16 fragment order:
//            BF[t][kk][lane][j] = M[t*16+(lane&15)][kk*32+(lane>>4)*8+j].
//            Serves as A-frag or B-frag (same index math; r13-r15 validated).
struct Tables {
    float          WB8T[24][24][8];
    unsigned short BF  [12][3][64][8];   // 36 KB
    int            S8[24];
};

constexpr int cfold(int idx, int n) {
    int p = 2 * n;
    int m = idx % p; if (m < 0) m += p;
    return (m >= n) ? (p - 1 - m) : m;
}

constexpr unsigned short cph(double v) {
    _Float16 h = (_Float16)(float)v;
    return __builtin_bit_cast(unsigned short, h);
}

constexpr Tables make_tables() {
    Tables T{};
    double cp[N_IN] = {}, minv[N_IN] = {};
    const double a = 1.0 / 6.0;
    minv[0] = 1.0 / (5.0 / 6.0);
    cp[0]   = a * minv[0];
    for (int i = 1; i < N_IN; ++i) {
        double bi = (i == N_IN - 1) ? (5.0 / 6.0) : (2.0 / 3.0);
        minv[i] = 1.0 / (bi - a * cp[i - 1]);
        cp[i]   = a * minv[i];
    }
    for (int j = 0; j < N_OUT; ++j) {
        double x = (double)j * 95.0 / 191.0;
        int    b = (int)x;
        double t = x - (double)b;
        double t2 = t * t, t3 = t2 * t;
        double w0 = (1.0 - t) * (1.0 - t) * (1.0 - t) / 6.0;
        double w1 = (3.0 * t3 - 6.0 * t2 + 4.0) / 6.0;
        double w2 = (-3.0 * t3 + 3.0 * t2 + 3.0 * t + 1.0) / 6.0;
        double w3 = t3 / 6.0;
        double r[N_IN] = {};
        r[cfold(b - 1, N_IN)] += w0;
        r[cfold(b,     N_IN)] += w1;
        r[cfold(b + 1, N_IN)] += w2;
        r[cfold(b + 2, N_IN)] += w3;
        double m[N_IN] = {};
        double dp = 0.0;
        for (int i = 0; i < N_IN; ++i) {
            dp = (i == 0) ? r[0] * minv[0] : (r[i] - a * dp) * minv[i];
            m[i] = dp;
        }
        double xv = 0.0;
        for (int i = N_IN - 1; i >= 0; --i) {
            xv = (i == N_IN - 1) ? m[i] : (m[i] - cp[i] * xv);
            m[i] = xv;
        }
        for (int k = 0; k < N_IN; ++k) {
            int kk = k >> 5, hi = (k >> 3) & 3, jj = k & 7;
            T.BF[j >> 4][kk][(hi << 4) | (j & 15)][jj] = cph(m[k]);
        }
        int s8 = ((j & ~7) * 95) / 191 - 9;
        if (s8 < 0) s8 = 0; if (s8 > 72) s8 = 72;
        if ((j & 7) == 0) T.S8[j >> 3] = s8;
        for (int tt = 0; tt < BW; ++tt)
            T.WB8T[j >> 3][tt][j & 7] = (float)m[s8 + tt];
    }
    return T;
}

__device__ const Tables TAB = make_tables();

// ---------------- pass 1: x-expansion (VALU, banded) ----------------
// in f32 [4][96][9216] -> T1h fp16 [4][192][9216]; blockIdx.y = output oct.
template <int QUADS>
__global__ __launch_bounds__(256)
void pass_x_kernel(const float4* __restrict__ in, uint2* __restrict__ outh) {
    int g  = blockIdx.x * 256 + threadIdx.x;
    int o  = g / QUADS;
    int q  = g - o * QUADS;
    int jo = blockIdx.y;
    int S  = TAB.S8[jo];
    const float4* ip = in + ((size_t)o * N_IN + S) * QUADS + q;
    const float4* wp = (const float4*)(&TAB.WB8T[jo][0][0]);  // wave-uniform
    float4 acc[8];
#pragma unroll
    for (int jj = 0; jj < 8; ++jj) acc[jj] = make_float4(0.f, 0.f, 0.f, 0.f);
#pragma unroll
    for (int t = 0; t < BW; ++t) {
        float4 v   = ip[(size_t)t * QUADS];
        float4 wlo = wp[2 * t];
        float4 whi = wp[2 * t + 1];
        fma4(acc[0], wlo.x, v); fma4(acc[1], wlo.y, v);
        fma4(acc[2], wlo.z, v); fma4(acc[3], wlo.w, v);
        fma4(acc[4], whi.x, v); fma4(acc[5], whi.y, v);
        fma4(acc[6], whi.z, v); fma4(acc[7], whi.w, v);
    }
    uint2* op = outh + ((size_t)o * N_OUT + jo * 8) * QUADS + q;
#pragma unroll
    for (int jj = 0; jj < 8; ++jj) {
        uint2 pk;
        pk.x = packh2(acc[jj].x, acc[jj].y);
        pk.y = packh2(acc[jj].z, acc[jj].w);
        op[(size_t)jj * QUADS] = pk;
    }
}

// ---------------- fused pass 2+3: pipelined dual GEMM on MFMA ----------------
// Block = slab o (768 blocks = 3/CU, fully co-resident), 384 threads = 6 waves.
// Software pipeline over zt (12 z'-tiles), double-buffered 16-row TzT tiles:
//   iter zt: barrier; A(zt+1) -> buf[(zt+1)&1]; B(zt) <- buf[zt&1] + NT stores
// The single loop-top barrier both (a) orders A(zt) before B(zt) and
// (b) orders B(zt-1) before A(zt+1)'s overwrite of its buffer.
// [r17 = session best, 44.5 µs. r18 (wider stages) and r19 (BF prefetch)
//  both regressed — residual is store-drain, not barriers/latency/width.]
// Plain __launch_bounds__ — min-waves arg spilled to scratch 3x (r6/r7/r9).
__global__ __launch_bounds__(384)
void pass_yz_kernel(const unsigned short* __restrict__ T1h,
                    float* __restrict__ out) {
    __shared__ unsigned short Tz[2][16 * TSP];   // 2 x 3.3 KB tiles
    int o    = blockIdx.x;             // 0..767
    int tid  = threadIdx.x;            // 0..383
    int w    = tid >> 6;               // wave 0..5
    int lane = tid & 63;
    int li   = lane & 15;
    int lg   = lane >> 4;

    const uint4* bf = (const uint4*)(&TAB.BF[0][0][0][0]);

    // GEMM-1 A-frags: slab rows (y-tile w), loaded once from global
    const unsigned short* ap = T1h + (size_t)o * N_IN * N_IN
                               + (size_t)(w * 16 + li) * N_IN + lg * 8;
    v8h a0 = as8h(*(const uint4*)(ap + 0));
    v8h a1 = as8h(*(const uint4*)(ap + 32));
    v8h a2 = as8h(*(const uint4*)(ap + 64));

    // GEMM-2 B-frags: y'-tiles {w, w+6}, persistent
    int ytA = w, ytB = w + 6;
    v8h bA0 = as8h(bf[(ytA * 3 + 0) * 64 + lane]);
    v8h bA1 = as8h(bf[(ytA * 3 + 1) * 64 + lane]);
    v8h bA2 = as8h(bf[(ytA * 3 + 2) * 64 + lane]);
    v8h bB0 = as8h(bf[(ytB * 3 + 0) * 64 + lane]);
    v8h bB1 = as8h(bf[(ytB * 3 + 1) * 64 + lane]);
    v8h bB2 = as8h(bf[(ytB * 3 + 2) * 64 + lane]);

    float* obase = out + (size_t)o * N_OUT * N_OUT;

    // GEMM-1 for z'-tile zt -> Tz[zt&1]
    auto gemm1 = [&](int zt) {
        int base = zt * 192 + lane;
        f32x4 acc = {0.f, 0.f, 0.f, 0.f};
        acc = __builtin_amdgcn_mfma_f32_16x16x32_f16(a0, as8h(bf[base]),       acc, 0, 0, 0);
        acc = __builtin_amdgcn_mfma_f32_16x16x32_f16(a1, as8h(bf[base + 64]),  acc, 0, 0, 0);
        acc = __builtin_amdgcn_mfma_f32_16x16x32_f16(a2, as8h(bf[base + 128]), acc, 0, 0, 0);
        // D[y][z']: col=li -> local z' row li; rows lg*4+i -> y (4 consec)
        uint2 pk;
        pk.x = packh2(acc.x, acc.y);
        pk.y = packh2(acc.z, acc.w);
        *(uint2*)(&Tz[zt & 1][li * TSP + w * 16 + lg * 4]) = pk;
    };

    gemm1(0);

    for (int zt = 0; zt < 12; ++zt) {
        __syncthreads();
        if (zt < 11) gemm1(zt + 1);        // fills buf[(zt+1)&1]
        // ---- GEMM-2 (transposed) consumes buf[zt&1] ----
        const unsigned short* ap2 = &Tz[zt & 1][li * TSP + lg * 8];
        v8h t0 = as8h(*(const uint4*)(ap2 + 0));
        v8h t1 = as8h(*(const uint4*)(ap2 + 32));
        v8h t2 = as8h(*(const uint4*)(ap2 + 64));
        f32x4 accA = {0.f, 0.f, 0.f, 0.f};
        accA = __builtin_amdgcn_mfma_f32_16x16x32_f16(t0, bA0, accA, 0, 0, 0);
        accA = __builtin_amdgcn_mfma_f32_16x16x32_f16(t1, bA1, accA, 0, 0, 0);
        accA = __builtin_amdgcn_mfma_f32_16x16x32_f16(t2, bA2, accA, 0, 0, 0);
        f32x4 accB = {0.f, 0.f, 0.f, 0.f};
        accB = __builtin_amdgcn_mfma_f32_16x16x32_f16(t0, bB0, accB, 0, 0, 0);
        accB = __builtin_amdgcn_mfma_f32_16x16x32_f16(t1, bB1, accB, 0, 0, 0);
        accB = __builtin_amdgcn_mfma_f32_16x16x32_f16(t2, bB2, accB, 0, 0, 0);
        // D'[z'][y']: col li -> y'; rows lg*4+i -> z' (4 consec) -> f32x4 NT
        float* opA = obase + (size_t)(ytA * 16 + li) * N_OUT + zt * 16 + lg * 4;
        __builtin_nontemporal_store(accA, (f32x4*)opA);
        float* opB = obase + (size_t)(ytB * 16 + li) * N_OUT + zt * 16 + lg * 4;
        __builtin_nontemporal_store(accB, (f32x4*)opB);
    }
}

extern "C" void kernel_launch(void* const* d_in, const int* in_sizes, int n_in,
                              void* d_out, int out_size, void* d_ws, size_t ws_size,
                              hipStream_t stream) {
    const float* in  = (const float*)d_in[0];
    float*       out = (float*)d_out;
    unsigned short* T1h = (unsigned short*)d_ws;  // [4][192][9216] fp16 = 14.2 MB

    // Pass 1: x-axis. in [4][96][2304 f4] -> T1h [4][192][2304 h4]
    {
        dim3 g(4 * 2304 / 256, BW, 1);  // (36, 24)
        pass_x_kernel<2304><<<g, 256, 0, stream>>>((const float4*)in, (uint2*)T1h);
    }
    // Fused pass 2+3: T1h [768 slabs][96][96] -> out [768][192][192]
    pass_yz_kernel<<<768, 384, 0, stream>>>(T1h, out);
}

// Round 21
// 41.665 us; speedup vs baseline: 1.2427x; 1.2427x over previous
//
#include <hip/hip_runtime.h>
#include <math.h>

#define N_IN  96
#define N_OUT 192
#define BW    24    // truncated band window width (pass_x only)
#define TSP   104   // TzT tile row stride in halfs (208B: 16B-aligned, 2-way max)

typedef _Float16 h2    __attribute__((ext_vector_type(2)));
typedef _Float16 v8h   __attribute__((ext_vector_type(8)));
typedef float    f32x4 __attribute__((ext_vector_type(4)));

__device__ __forceinline__ unsigned int packh2(float a, float b) {
    h2 h; h.x = (_Float16)a; h.y = (_Float16)b;
    return __builtin_bit_cast(unsigned int, h);
}

__device__ __forceinline__ void fma4(float4& a, float w, const float4& v) {
    a.x += w * v.x; a.y += w * v.y; a.z += w * v.z; a.w += w * v.w;
}

__device__ __forceinline__ v8h as8h(const uint4& u) {
    return __builtin_bit_cast(v8h, u);
}

// ---------------- compile-time weight tables ----------------
// M = B_resize(192x96) * A^-1 (A tridiag: diag 2/3, 5/6 at ends, off 1/6),
// constexpr Thomas solve.
//  WB8T/S8 : banded f32 weights for pass_x (window BW=24).
//  BF      : dense fp16 M in mfma_f32_16x16x32_f16 fragment order:
//            BF[t][kk][lane][j] = M[t*16+(lane&15)][kk*32+(lane>>4)*8+j].
//            Serves as A-frag or B-frag (same index math; r13-r15 validated).
struct Tables {
    float          WB8T[24][24][8];
    unsigned short BF  [12][3][64][8];   // 36 KB
    int            S8[24];
};

constexpr int cfold(int idx, int n) {
    int p = 2 * n;
    int m = idx % p; if (m < 0) m += p;
    return (m >= n) ? (p - 1 - m) : m;
}

constexpr unsigned short cph(double v) {
    _Float16 h = (_Float16)(float)v;
    return __builtin_bit_cast(unsigned short, h);
}

constexpr Tables make_tables() {
    Tables T{};
    double cp[N_IN] = {}, minv[N_IN] = {};
    const double a = 1.0 / 6.0;
    minv[0] = 1.0 / (5.0 / 6.0);
    cp[0]   = a * minv[0];
    for (int i = 1; i < N_IN; ++i) {
        double bi = (i == N_IN - 1) ? (5.0 / 6.0) : (2.0 / 3.0);
        minv[i] = 1.0 / (bi - a * cp[i - 1]);
        cp[i]   = a * minv[i];
    }
    for (int j = 0; j < N_OUT; ++j) {
        double x = (double)j * 95.0 / 191.0;
        int    b = (int)x;
        double t = x - (double)b;
        double t2 = t * t, t3 = t2 * t;
        double w0 = (1.0 - t) * (1.0 - t) * (1.0 - t) / 6.0;
        double w1 = (3.0 * t3 - 6.0 * t2 + 4.0) / 6.0;
        double w2 = (-3.0 * t3 + 3.0 * t2 + 3.0 * t + 1.0) / 6.0;
        double w3 = t3 / 6.0;
        double r[N_IN] = {};
        r[cfold(b - 1, N_IN)] += w0;
        r[cfold(b,     N_IN)] += w1;
        r[cfold(b + 1, N_IN)] += w2;
        r[cfold(b + 2, N_IN)] += w3;
        double m[N_IN] = {};
        double dp = 0.0;
        for (int i = 0; i < N_IN; ++i) {
            dp = (i == 0) ? r[0] * minv[0] : (r[i] - a * dp) * minv[i];
            m[i] = dp;
        }
        double xv = 0.0;
        for (int i = N_IN - 1; i >= 0; --i) {
            xv = (i == N_IN - 1) ? m[i] : (m[i] - cp[i] * xv);
            m[i] = xv;
        }
        for (int k = 0; k < N_IN; ++k) {
            int kk = k >> 5, hi = (k >> 3) & 3, jj = k & 7;
            T.BF[j >> 4][kk][(hi << 4) | (j & 15)][jj] = cph(m[k]);
        }
        int s8 = ((j & ~7) * 95) / 191 - 9;
        if (s8 < 0) s8 = 0; if (s8 > 72) s8 = 72;
        if ((j & 7) == 0) T.S8[j >> 3] = s8;
        for (int tt = 0; tt < BW; ++tt)
            T.WB8T[j >> 3][tt][j & 7] = (float)m[s8 + tt];
    }
    return T;
}

__device__ const Tables TAB = make_tables();

// ---------------- pass 1: x-expansion (VALU, banded) ----------------
// in f32 [4][96][9216] -> T1h fp16 [4][192][9216]; blockIdx.y = output oct.
template <int QUADS>
__global__ __launch_bounds__(256)
void pass_x_kernel(const float4* __restrict__ in, uint2* __restrict__ outh) {
    int g  = blockIdx.x * 256 + threadIdx.x;
    int o  = g / QUADS;
    int q  = g - o * QUADS;
    int jo = blockIdx.y;
    int S  = TAB.S8[jo];
    const float4* ip = in + ((size_t)o * N_IN + S) * QUADS + q;
    const float4* wp = (const float4*)(&TAB.WB8T[jo][0][0]);  // wave-uniform
    float4 acc[8];
#pragma unroll
    for (int jj = 0; jj < 8; ++jj) acc[jj] = make_float4(0.f, 0.f, 0.f, 0.f);
#pragma unroll
    for (int t = 0; t < BW; ++t) {
        float4 v   = ip[(size_t)t * QUADS];
        float4 wlo = wp[2 * t];
        float4 whi = wp[2 * t + 1];
        fma4(acc[0], wlo.x, v); fma4(acc[1], wlo.y, v);
        fma4(acc[2], wlo.z, v); fma4(acc[3], wlo.w, v);
        fma4(acc[4], whi.x, v); fma4(acc[5], whi.y, v);
        fma4(acc[6], whi.z, v); fma4(acc[7], whi.w, v);
    }
    uint2* op = outh + ((size_t)o * N_OUT + jo * 8) * QUADS + q;
#pragma unroll
    for (int jj = 0; jj < 8; ++jj) {
        uint2 pk;
        pk.x = packh2(acc[jj].x, acc[jj].y);
        pk.y = packh2(acc[jj].z, acc[jj].w);
        op[(size_t)jj * QUADS] = pk;
    }
}

// ---------------- fused pass 2+3: pipelined dual GEMM on MFMA ----------------
// Block = slab o (768 blocks = 3/CU, fully co-resident), 384 threads = 6 waves.
// Software pipeline over zt (12 z'-tiles), double-buffered 16-row TzT tiles:
//   iter zt: barrier; A(zt+1) -> buf[(zt+1)&1]; B(zt) <- buf[zt&1] + stores
// The single loop-top barrier both (a) orders A(zt) before B(zt) and
// (b) orders B(zt-1) before A(zt+1)'s overwrite of its buffer.
// r21 change vs r17 (44.5/51.8 µs, noise ±8%): stores are PLAIN (not NT) —
// NT plausibly bypasses L2 write-combining, turning the column-marching
// 64B-per-row store pattern into scattered DRAM transactions; cached stores
// let L2 accumulate full lines per 144KB contiguous block region (the 7 TB/s
// fill kernel uses cached stores).
// Plain __launch_bounds__ — min-waves arg spilled to scratch 3x (r6/r7/r9).
__global__ __launch_bounds__(384)
void pass_yz_kernel(const unsigned short* __restrict__ T1h,
                    float* __restrict__ out) {
    __shared__ unsigned short Tz[2][16 * TSP];   // 2 x 3.3 KB tiles
    int o    = blockIdx.x;             // 0..767
    int tid  = threadIdx.x;            // 0..383
    int w    = tid >> 6;               // wave 0..5
    int lane = tid & 63;
    int li   = lane & 15;
    int lg   = lane >> 4;

    const uint4* bf = (const uint4*)(&TAB.BF[0][0][0][0]);

    // GEMM-1 A-frags: slab rows (y-tile w), loaded once from global
    const unsigned short* ap = T1h + (size_t)o * N_IN * N_IN
                               + (size_t)(w * 16 + li) * N_IN + lg * 8;
    v8h a0 = as8h(*(const uint4*)(ap + 0));
    v8h a1 = as8h(*(const uint4*)(ap + 32));
    v8h a2 = as8h(*(const uint4*)(ap + 64));

    // GEMM-2 B-frags: y'-tiles {w, w+6}, persistent
    int ytA = w, ytB = w + 6;
    v8h bA0 = as8h(bf[(ytA * 3 + 0) * 64 + lane]);
    v8h bA1 = as8h(bf[(ytA * 3 + 1) * 64 + lane]);
    v8h bA2 = as8h(bf[(ytA * 3 + 2) * 64 + lane]);
    v8h bB0 = as8h(bf[(ytB * 3 + 0) * 64 + lane]);
    v8h bB1 = as8h(bf[(ytB * 3 + 1) * 64 + lane]);
    v8h bB2 = as8h(bf[(ytB * 3 + 2) * 64 + lane]);

    float* obase = out + (size_t)o * N_OUT * N_OUT;

    // GEMM-1 for z'-tile zt -> Tz[zt&1]
    auto gemm1 = [&](int zt) {
        int base = zt * 192 + lane;
        f32x4 acc = {0.f, 0.f, 0.f, 0.f};
        acc = __builtin_amdgcn_mfma_f32_16x16x32_f16(a0, as8h(bf[base]),       acc, 0, 0, 0);
        acc = __builtin_amdgcn_mfma_f32_16x16x32_f16(a1, as8h(bf[base + 64]),  acc, 0, 0, 0);
        acc = __builtin_amdgcn_mfma_f32_16x16x32_f16(a2, as8h(bf[base + 128]), acc, 0, 0, 0);
        // D[y][z']: col=li -> local z' row li; rows lg*4+i -> y (4 consec)
        uint2 pk;
        pk.x = packh2(acc.x, acc.y);
        pk.y = packh2(acc.z, acc.w);
        *(uint2*)(&Tz[zt & 1][li * TSP + w * 16 + lg * 4]) = pk;
    };

    gemm1(0);

    for (int zt = 0; zt < 12; ++zt) {
        __syncthreads();
        if (zt < 11) gemm1(zt + 1);        // fills buf[(zt+1)&1]
        // ---- GEMM-2 (transposed) consumes buf[zt&1] ----
        const unsigned short* ap2 = &Tz[zt & 1][li * TSP + lg * 8];
        v8h t0 = as8h(*(const uint4*)(ap2 + 0));
        v8h t1 = as8h(*(const uint4*)(ap2 + 32));
        v8h t2 = as8h(*(const uint4*)(ap2 + 64));
        f32x4 accA = {0.f, 0.f, 0.f, 0.f};
        accA = __builtin_amdgcn_mfma_f32_16x16x32_f16(t0, bA0, accA, 0, 0, 0);
        accA = __builtin_amdgcn_mfma_f32_16x16x32_f16(t1, bA1, accA, 0, 0, 0);
        accA = __builtin_amdgcn_mfma_f32_16x16x32_f16(t2, bA2, accA, 0, 0, 0);
        f32x4 accB = {0.f, 0.f, 0.f, 0.f};
        accB = __builtin_amdgcn_mfma_f32_16x16x32_f16(t0, bB0, accB, 0, 0, 0);
        accB = __builtin_amdgcn_mfma_f32_16x16x32_f16(t1, bB1, accB, 0, 0, 0);
        accB = __builtin_amdgcn_mfma_f32_16x16x32_f16(t2, bB2, accB, 0, 0, 0);
        // D'[z'][y']: col li -> y'; rows lg*4+i -> z' (4 consec) -> f32x4
        *(f32x4*)(obase + (size_t)(ytA * 16 + li) * N_OUT + zt * 16 + lg * 4) = accA;
        *(f32x4*)(obase + (size_t)(ytB * 16 + li) * N_OUT + zt * 16 + lg * 4) = accB;
    }
}

extern "C" void kernel_launch(void* const* d_in, const int* in_sizes, int n_in,
                              void* d_out, int out_size, void* d_ws, size_t ws_size,
                              hipStream_t stream) {
    const float* in  = (const float*)d_in[0];
    float*       out = (float*)d_out;
    unsigned short* T1h = (unsigned short*)d_ws;  // [4][192][9216] fp16 = 14.2 MB

    // Pass 1: x-axis. in [4][96][2304 f4] -> T1h [4][192][2304 h4]
    {
        dim3 g(4 * 2304 / 256, BW, 1);  // (36, 24)
        pass_x_kernel<2304><<<g, 256, 0, stream>>>((const float4*)in, (uint2*)T1h);
    }
    // Fused pass 2+3: T1h [768 slabs][96][96] -> out [768][192][192]
    pass_yz_kernel<<<768, 384, 0, stream>>>(T1h, out);
}

// Round 22
// 39.998 us; speedup vs baseline: 1.2945x; 1.0417x over previous
//
#include <hip/hip_runtime.h>
#include <math.h>

#define N_IN  96
#define N_OUT 192
#define BW    24    // truncated band window width (pass_x only)
#define TSP   104   // TzT tile row stride in halfs (208B: 16B-aligned, 2-way max)

typedef _Float16 h2    __attribute__((ext_vector_type(2)));
typedef _Float16 v8h   __attribute__((ext_vector_type(8)));
typedef float    f32x4 __attribute__((ext_vector_type(4)));

__device__ __forceinline__ unsigned int packh2(float a, float b) {
    h2 h; h.x = (_Float16)a; h.y = (_Float16)b;
    return __builtin_bit_cast(unsigned int, h);
}

__device__ __forceinline__ void fma4(float4& a, float w, const float4& v) {
    a.x += w * v.x; a.y += w * v.y; a.z += w * v.z; a.w += w * v.w;
}

__device__ __forceinline__ v8h as8h(const uint4& u) {
    return __builtin_bit_cast(v8h, u);
}

// ---------------- compile-time weight tables ----------------
// M = B_resize(192x96) * A^-1 (A tridiag: diag 2/3, 5/6 at ends, off 1/6),
// constexpr Thomas solve.
//  WB8T/S8 : banded f32 weights for pass_x (window BW=24).
//  BF      : dense fp16 M in mfma_f32_16x16x32_f16 fragment order:
//            BF[t][kk][lane][j] = M[t*16+(lane&15)][kk*32+(lane>>4)*8+j].
//            Serves as A-frag or B-frag (same index math; r13-r15 validated).
struct Tables {
    float          WB8T[24][24][8];
    unsigned short BF  [12][3][64][8];   // 36 KB
    int            S8[24];
};

constexpr int cfold(int idx, int n) {
    int p = 2 * n;
    int m = idx % p; if (m < 0) m += p;
    return (m >= n) ? (p - 1 - m) : m;
}

constexpr unsigned short cph(double v) {
    _Float16 h = (_Float16)(float)v;
    return __builtin_bit_cast(unsigned short, h);
}

constexpr Tables make_tables() {
    Tables T{};
    double cp[N_IN] = {}, minv[N_IN] = {};
    const double a = 1.0 / 6.0;
    minv[0] = 1.0 / (5.0 / 6.0);
    cp[0]   = a * minv[0];
    for (int i = 1; i < N_IN; ++i) {
        double bi = (i == N_IN - 1) ? (5.0 / 6.0) : (2.0 / 3.0);
        minv[i] = 1.0 / (bi - a * cp[i - 1]);
        cp[i]   = a * minv[i];
    }
    for (int j = 0; j < N_OUT; ++j) {
        double x = (double)j * 95.0 / 191.0;
        int    b = (int)x;
        double t = x - (double)b;
        double t2 = t * t, t3 = t2 * t;
        double w0 = (1.0 - t) * (1.0 - t) * (1.0 - t) / 6.0;
        double w1 = (3.0 * t3 - 6.0 * t2 + 4.0) / 6.0;
        double w2 = (-3.0 * t3 + 3.0 * t2 + 3.0 * t + 1.0) / 6.0;
        double w3 = t3 / 6.0;
        double r[N_IN] = {};
        r[cfold(b - 1, N_IN)] += w0;
        r[cfold(b,     N_IN)] += w1;
        r[cfold(b + 1, N_IN)] += w2;
        r[cfold(b + 2, N_IN)] += w3;
        double m[N_IN] = {};
        double dp = 0.0;
        for (int i = 0; i < N_IN; ++i) {
            dp = (i == 0) ? r[0] * minv[0] : (r[i] - a * dp) * minv[i];
            m[i] = dp;
        }
        double xv = 0.0;
        for (int i = N_IN - 1; i >= 0; --i) {
            xv = (i == N_IN - 1) ? m[i] : (m[i] - cp[i] * xv);
            m[i] = xv;
        }
        for (int k = 0; k < N_IN; ++k) {
            int kk = k >> 5, hi = (k >> 3) & 3, jj = k & 7;
            T.BF[j >> 4][kk][(hi << 4) | (j & 15)][jj] = cph(m[k]);
        }
        int s8 = ((j & ~7) * 95) / 191 - 9;
        if (s8 < 0) s8 = 0; if (s8 > 72) s8 = 72;
        if ((j & 7) == 0) T.S8[j >> 3] = s8;
        for (int tt = 0; tt < BW; ++tt)
            T.WB8T[j >> 3][tt][j & 7] = (float)m[s8 + tt];
    }
    return T;
}

__device__ const Tables TAB = make_tables();

// ---------------- pass 1: x-expansion (VALU, banded) ----------------
// in f32 [4][96][9216] -> T1h fp16 [4][192][9216]; blockIdx.y = output oct.
template <int QUADS>
__global__ __launch_bounds__(256)
void pass_x_kernel(const float4* __restrict__ in, uint2* __restrict__ outh) {
    int g  = blockIdx.x * 256 + threadIdx.x;
    int o  = g / QUADS;
    int q  = g - o * QUADS;
    int jo = blockIdx.y;
    int S  = TAB.S8[jo];
    const float4* ip = in + ((size_t)o * N_IN + S) * QUADS + q;
    const float4* wp = (const float4*)(&TAB.WB8T[jo][0][0]);  // wave-uniform
    float4 acc[8];
#pragma unroll
    for (int jj = 0; jj < 8; ++jj) acc[jj] = make_float4(0.f, 0.f, 0.f, 0.f);
#pragma unroll
    for (int t = 0; t < BW; ++t) {
        float4 v   = ip[(size_t)t * QUADS];
        float4 wlo = wp[2 * t];
        float4 whi = wp[2 * t + 1];
        fma4(acc[0], wlo.x, v); fma4(acc[1], wlo.y, v);
        fma4(acc[2], wlo.z, v); fma4(acc[3], wlo.w, v);
        fma4(acc[4], whi.x, v); fma4(acc[5], whi.y, v);
        fma4(acc[6], whi.z, v); fma4(acc[7], whi.w, v);
    }
    uint2* op = outh + ((size_t)o * N_OUT + jo * 8) * QUADS + q;
#pragma unroll
    for (int jj = 0; jj < 8; ++jj) {
        uint2 pk;
        pk.x = packh2(acc[jj].x, acc[jj].y);
        pk.y = packh2(acc[jj].z, acc[jj].w);
        op[(size_t)jj * QUADS] = pk;
    }
}

// ---------------- fused pass 2+3: pipelined dual GEMM on MFMA ----------------
// Block = slab o (768 blocks = 3/CU, fully co-resident), 384 threads = 6 waves.
// Software pipeline over zt (12 z'-tiles), double-buffered 16-row TzT tiles:
//   iter zt: barrier; A(zt+1) -> buf[(zt+1)&1]; B(zt) <- buf[zt&1] + stores
// Stores are PLAIN (r21: dropping NT let L2 write-combine -> session best
// 41.7 µs). r22 change: T5 s_setprio(1) around the MFMA clusters — the
// per-stage wave role-split (load-issuing vs MFMA+store) is exactly the
// structure where setprio pays (catalog m218b); null on lockstep schedules.
// Plain __launch_bounds__ — min-waves arg spilled to scratch 3x (r6/r7/r9).
__global__ __launch_bounds__(384)
void pass_yz_kernel(const unsigned short* __restrict__ T1h,
                    float* __restrict__ out) {
    __shared__ unsigned short Tz[2][16 * TSP];   // 2 x 3.3 KB tiles
    int o    = blockIdx.x;             // 0..767
    int tid  = threadIdx.x;            // 0..383
    int w    = tid >> 6;               // wave 0..5
    int lane = tid & 63;
    int li   = lane & 15;
    int lg   = lane >> 4;

    const uint4* bf = (const uint4*)(&TAB.BF[0][0][0][0]);

    // GEMM-1 A-frags: slab rows (y-tile w), loaded once from global
    const unsigned short* ap = T1h + (size_t)o * N_IN * N_IN
                               + (size_t)(w * 16 + li) * N_IN + lg * 8;
    v8h a0 = as8h(*(const uint4*)(ap + 0));
    v8h a1 = as8h(*(const uint4*)(ap + 32));
    v8h a2 = as8h(*(const uint4*)(ap + 64));

    // GEMM-2 B-frags: y'-tiles {w, w+6}, persistent
    int ytA = w, ytB = w + 6;
    v8h bA0 = as8h(bf[(ytA * 3 + 0) * 64 + lane]);
    v8h bA1 = as8h(bf[(ytA * 3 + 1) * 64 + lane]);
    v8h bA2 = as8h(bf[(ytA * 3 + 2) * 64 + lane]);
    v8h bB0 = as8h(bf[(ytB * 3 + 0) * 64 + lane]);
    v8h bB1 = as8h(bf[(ytB * 3 + 1) * 64 + lane]);
    v8h bB2 = as8h(bf[(ytB * 3 + 2) * 64 + lane]);

    float* obase = out + (size_t)o * N_OUT * N_OUT;

    // GEMM-1 for z'-tile zt -> Tz[zt&1]
    auto gemm1 = [&](int zt) {
        int base = zt * 192 + lane;
        uint4 b0 = bf[base], b1 = bf[base + 64], b2 = bf[base + 128];
        __builtin_amdgcn_s_setprio(1);
        f32x4 acc = {0.f, 0.f, 0.f, 0.f};
        acc = __builtin_amdgcn_mfma_f32_16x16x32_f16(a0, as8h(b0), acc, 0, 0, 0);
        acc = __builtin_amdgcn_mfma_f32_16x16x32_f16(a1, as8h(b1), acc, 0, 0, 0);
        acc = __builtin_amdgcn_mfma_f32_16x16x32_f16(a2, as8h(b2), acc, 0, 0, 0);
        __builtin_amdgcn_s_setprio(0);
        // D[y][z']: col=li -> local z' row li; rows lg*4+i -> y (4 consec)
        uint2 pk;
        pk.x = packh2(acc.x, acc.y);
        pk.y = packh2(acc.z, acc.w);
        *(uint2*)(&Tz[zt & 1][li * TSP + w * 16 + lg * 4]) = pk;
    };

    gemm1(0);

    for (int zt = 0; zt < 12; ++zt) {
        __syncthreads();
        if (zt < 11) gemm1(zt + 1);        // fills buf[(zt+1)&1]
        // ---- GEMM-2 (transposed) consumes buf[zt&1] ----
        const unsigned short* ap2 = &Tz[zt & 1][li * TSP + lg * 8];
        v8h t0 = as8h(*(const uint4*)(ap2 + 0));
        v8h t1 = as8h(*(const uint4*)(ap2 + 32));
        v8h t2 = as8h(*(const uint4*)(ap2 + 64));
        __builtin_amdgcn_s_setprio(1);
        f32x4 accA = {0.f, 0.f, 0.f, 0.f};
        accA = __builtin_amdgcn_mfma_f32_16x16x32_f16(t0, bA0, accA, 0, 0, 0);
        accA = __builtin_amdgcn_mfma_f32_16x16x32_f16(t1, bA1, accA, 0, 0, 0);
        accA = __builtin_amdgcn_mfma_f32_16x16x32_f16(t2, bA2, accA, 0, 0, 0);
        f32x4 accB = {0.f, 0.f, 0.f, 0.f};
        accB = __builtin_amdgcn_mfma_f32_16x16x32_f16(t0, bB0, accB, 0, 0, 0);
        accB = __builtin_amdgcn_mfma_f32_16x16x32_f16(t1, bB1, accB, 0, 0, 0);
        accB = __builtin_amdgcn_mfma_f32_16x16x32_f16(t2, bB2, accB, 0, 0, 0);
        __builtin_amdgcn_s_setprio(0);
        // D'[z'][y']: col li -> y'; rows lg*4+i -> z' (4 consec) -> f32x4
        *(f32x4*)(obase + (size_t)(ytA * 16 + li) * N_OUT + zt * 16 + lg * 4) = accA;
        *(f32x4*)(obase + (size_t)(ytB * 16 + li) * N_OUT + zt * 16 + lg * 4) = accB;
    }
}

extern "C" void kernel_launch(void* const* d_in, const int* in_sizes, int n_in,
                              void* d_out, int out_size, void* d_ws, size_t ws_size,
                              hipStream_t stream) {
    const float* in  = (const float*)d_in[0];
    float*       out = (float*)d_out;
    unsigned short* T1h = (unsigned short*)d_ws;  // [4][192][9216] fp16 = 14.2 MB

    // Pass 1: x-axis. in [4][96][2304 f4] -> T1h [4][192][2304 h4]
    {
        dim3 g(4 * 2304 / 256, BW, 1);  // (36, 24)
        pass_x_kernel<2304><<<g, 256, 0, stream>>>((const float4*)in, (uint2*)T1h);
    }
    // Fused pass 2+3: T1h [768 slabs][96][96] -> out [768][192][192]
    pass_yz_kernel<<<768, 384, 0, stream>>>(T1h, out);
}